// Round 19
// baseline (169.123 us; speedup 1.0000x reference)
//
#include <hip/hip_runtime.h>
#include <cstdint>
#include <cstddef>

// Problem constants (reference: B=8, S=4096, N_STATE=1024, N_HEAD=16)
#define S_LEN   4096
#define NROT    32
#define NGRP    8192    // groups of 64 rows; one wave per group, lane = row

typedef __attribute__((ext_vector_type(4))) float floatx4;

// ---------------------------------------------------------------------------
// Setup: blocks 0..511 fill the interleaved cos/sin table (4096 x 32 float2).
// Block 512: compose M = G0..G31 * R (fp32, row-major, 64x64) into d_ws.
// ---------------------------------------------------------------------------
__global__ void setup_kernel(const float* __restrict__ thetas,
                             const float* __restrict__ theta_scale,
                             const float* __restrict__ r_matrix,
                             const int*   __restrict__ r_pairs,
                             const float* __restrict__ inv_freq,
                             float* __restrict__ Mg,
                             float2* __restrict__ csT) {
  if (blockIdx.x < 512) {
    int idx = blockIdx.x * 256 + threadIdx.x;   // 0..131071 = s*32 + f
    int s = idx >> 5;
    int f = idx & 31;
    float ang = (float)s * inv_freq[f];
    csT[idx] = make_float2(cosf(ang), sinf(ang));
    return;
  }
  __shared__ float C[64 * 65];
  int tid = threadIdx.x;
  if (tid < 64) {
    for (int c = 0; c < 64; ++c) C[tid * 65 + c] = (tid == c) ? 1.0f : 0.0f;
    float sc = theta_scale[0];
    for (int q = 0; q < NROT; ++q) {
      float th = thetas[q] * sc;
      float cs = cosf(th), sn = sinf(th);
      int i = r_pairs[2 * q], j = r_pairs[2 * q + 1];
      float xi = C[tid * 65 + i];
      float xj = C[tid * 65 + j];
      C[tid * 65 + i] =  xi * cs + xj * sn;
      C[tid * 65 + j] = -xi * sn + xj * cs;
    }
  }
  __syncthreads();
  // Mg[t][c] = sum_k C[t][k] * R[k][c]  (row-major fp32)
  for (int o = tid; o < 64 * 64; o += 256) {
    int t = o >> 6, c = o & 63;
    float a = 0.0f;
    for (int k = 0; k < 64; ++k) a = fmaf(C[t * 65 + k], r_matrix[k * 64 + c], a);
    Mg[o] = a;
  }
}

// ---------------------------------------------------------------------------
// Main R19: NO LDS, NO MFMA, NO barriers, NO manual waits — the transpose
// goes through the cache. Lane owns one full row (64 fp32, 16 dwordx4 at
// 256B lane stride; per-instruction uncoalesced but the 16 back-to-back
// loads cover every byte -> L2 merges; same for stores). Matmul on the
// VALU with M streamed via SGPRs: M + k*64 + p*16 is wave-uniform ->
// s_load_dwordx16 (constant-cache-hot), v_fma with SGPR operand.
// 4 passes: pass p computes y-cols [16p,16p+16) = 64x16 FMA (acc[16]),
// which is exactly RoPE d-range [8p, 8p+8): out[d] = y[2d]c - y[2d+1]s,
// out[32+d] = y[2d]s + y[2d+1]c — fully in-lane. Full fp32 precision.
// Per-wave streams are independent (copy-kernel-like); waves never convoy
// on LDS drains because there are none. 2048 blocks x 4 waves.
// ---------------------------------------------------------------------------
__global__ __launch_bounds__(256)
void rotary_main(const float* __restrict__ x,
                 const float* __restrict__ Mg,
                 const float* __restrict__ csT,
                 float* __restrict__ out) {
  const int tid  = threadIdx.x;
  const int lane = tid & 63;
  const int wid  = tid >> 6;
  const int w    = blockIdx.x * 4 + wid;        // wave id = group id 0..8191

  const float* xr = x   + (size_t)w * 4096 + (size_t)lane * 64;  // my row
  float*       orow = out + (size_t)w * 4096 + (size_t)lane * 64;

  // ---- load my entire row: 16 dwordx4, all independent, issued up front --
  float xf[64];
  #pragma unroll
  for (int j = 0; j < 16; ++j)
    *reinterpret_cast<floatx4*>(&xf[j * 4]) =
        *reinterpret_cast<const floatx4*>(xr + j * 4);

  // sequence position for my row
  const int s = ((w * 64 + lane) >> 4) & (S_LEN - 1);
  const float* csrow = csT + (size_t)s * 64;    // 32 interleaved (c,s) pairs

  // ---- 4 passes over output quarters (dynamic loop: keeps code ~9KB) ----
  #pragma unroll 1
  for (int p = 0; p < 4; ++p) {
    // cos/sin for d in [8p, 8p+8): 8 (c,s) pairs = 4 float4
    float4 cs0 = *reinterpret_cast<const float4*>(csrow + p * 16);
    float4 cs1 = *reinterpret_cast<const float4*>(csrow + p * 16 + 4);
    float4 cs2 = *reinterpret_cast<const float4*>(csrow + p * 16 + 8);
    float4 cs3 = *reinterpret_cast<const float4*>(csrow + p * 16 + 12);

    // acc[j] = y[row][p*16 + j]
    float acc[16];
    #pragma unroll
    for (int j = 0; j < 16; ++j) acc[j] = 0.0f;

    const float* Mp = Mg + p * 16;              // wave-uniform base
    #pragma unroll
    for (int k = 0; k < 64; ++k) {
      const float* Mk = Mp + k * 64;            // uniform -> s_load_dwordx16
      const float xk = xf[k];                   // static index (unrolled)
      #pragma unroll
      for (int j = 0; j < 16; ++j)
        acc[j] = fmaf(xk, Mk[j], acc[j]);
    }

    // RoPE: d = p*8 + j; out[d] = y[2d]c - y[2d+1]s; out[32+d] = y[2d]s + y[2d+1]c
    const float cd[8] = {cs0.x, cs0.z, cs1.x, cs1.z, cs2.x, cs2.z, cs3.x, cs3.z};
    const float sd[8] = {cs0.y, cs0.w, cs1.y, cs1.w, cs2.y, cs2.w, cs3.y, cs3.w};
    float lo[8], hi[8];
    #pragma unroll
    for (int j = 0; j < 8; ++j) {
      const float y1 = acc[2 * j];
      const float y2 = acc[2 * j + 1];
      lo[j] = fmaf(y1, cd[j], -(y2 * sd[j]));
      hi[j] = fmaf(y1, sd[j],   y2 * cd[j]);
    }
    *reinterpret_cast<floatx4*>(orow + p * 8)          = *(floatx4*)&lo[0];
    *reinterpret_cast<floatx4*>(orow + p * 8 + 4)      = *(floatx4*)&lo[4];
    *reinterpret_cast<floatx4*>(orow + 32 + p * 8)     = *(floatx4*)&hi[0];
    *reinterpret_cast<floatx4*>(orow + 32 + p * 8 + 4) = *(floatx4*)&hi[4];
  }
}

extern "C" void kernel_launch(void* const* d_in, const int* in_sizes, int n_in,
                              void* d_out, int out_size, void* d_ws, size_t ws_size,
                              hipStream_t stream) {
  const float* x           = (const float*)d_in[0];
  const float* thetas      = (const float*)d_in[1];
  const float* theta_scale = (const float*)d_in[2];
  const float* r_matrix    = (const float*)d_in[3];
  const float* inv_freq    = (const float*)d_in[4];
  const int*   r_pairs     = (const int*)d_in[5];

  float*  Mg  = (float*)d_ws;                   // 4096 floats (16KB)
  float2* csT = (float2*)((char*)d_ws + 16384); // 4096*32*8B = 1MB
  float*  outp = (float*)d_out;

  setup_kernel<<<513, 256, 0, stream>>>(thetas, theta_scale, r_matrix, r_pairs,
                                        inv_freq, Mg, csT);
  rotary_main<<<NGRP / 4, 256, 0, stream>>>(x, Mg, (const float*)csT, outp);
}

// Round 20
// 71.263 us; speedup vs baseline: 2.3732x; 2.3732x over previous
//
#include <hip/hip_runtime.h>
#include <cstdint>
#include <cstddef>

// Problem constants (reference: B=8, S=4096, N_STATE=1024, N_HEAD=16)
#define S_LEN   4096
#define NROT    32
#define NGRP    8192    // groups of 64 rows (64x64 fp32 tile each)

typedef __attribute__((ext_vector_type(8))) short  short8x;  // 8 bf16 (4 VGPR)
typedef __attribute__((ext_vector_type(4))) float  floatx4;  // 4 f32

typedef __attribute__((address_space(1))) unsigned int gu32;
typedef __attribute__((address_space(3))) unsigned int lu32;

__device__ __host__ inline unsigned short f2bf(float f) {
  union { float f; unsigned u; } c; c.f = f;
  unsigned u = c.u;
  return (unsigned short)((u + 0x7fffu + ((u >> 16) & 1u)) >> 16);
}
__device__ inline float bf2f(unsigned short h) {
  union { unsigned u; float f; } c; c.u = ((unsigned)h) << 16;
  return c.f;
}

// ---------------------------------------------------------------------------
// Setup: blocks 0..511 fill the interleaved cos/sin table (4096 x 32 float2).
// Block 512: compose M = G0..G31 * R, emit 8 RNE-bf16 M^T-fragments
// (nt x ks; x keeps its hi/lo split so the dominant precision path stays):
//   Bfrag[(nt*2+ks)*64 + lane] = 8 bf16:
//     M[k = ks*32 + (lane>>4)*8 + j][col = nt*16 + (lane&15)]
// ---------------------------------------------------------------------------
__global__ void setup_kernel(const float* __restrict__ thetas,
                             const float* __restrict__ theta_scale,
                             const float* __restrict__ r_matrix,
                             const int*   __restrict__ r_pairs,
                             const float* __restrict__ inv_freq,
                             uint4* __restrict__ Bfrag,
                             float2* __restrict__ csT) {
  if (blockIdx.x < 512) {
    int idx = blockIdx.x * 256 + threadIdx.x;   // 0..131071 = s*32 + f
    int s = idx >> 5;
    int f = idx & 31;
    float ang = (float)s * inv_freq[f];
    csT[idx] = make_float2(cosf(ang), sinf(ang));
    return;
  }
  __shared__ float C[64 * 65];
  __shared__ float Mm[64 * 64];
  int tid = threadIdx.x;
  if (tid < 64) {
    for (int c = 0; c < 64; ++c) C[tid * 65 + c] = (tid == c) ? 1.0f : 0.0f;
    float sc = theta_scale[0];
    for (int q = 0; q < NROT; ++q) {
      float th = thetas[q] * sc;
      float cs = cosf(th), sn = sinf(th);
      int i = r_pairs[2 * q], j = r_pairs[2 * q + 1];
      float xi = C[tid * 65 + i];
      float xj = C[tid * 65 + j];
      C[tid * 65 + i] =  xi * cs + xj * sn;
      C[tid * 65 + j] = -xi * sn + xj * cs;
    }
  }
  __syncthreads();
  for (int o = tid; o < 64 * 64; o += 256) {
    int t = o >> 6, c = o & 63;
    float a = 0.0f;
    for (int k = 0; k < 64; ++k) a = fmaf(C[t * 65 + k], r_matrix[k * 64 + c], a);
    Mm[o] = a;
  }
  __syncthreads();
  for (int e = tid; e < 8 * 64; e += 256) {
    int f = e >> 6, l = e & 63;
    int ks = f & 1, nt = f >> 1;
    int col = nt * 16 + (l & 15);
    unsigned short w[8];
    for (int j = 0; j < 8; ++j) {
      int k = ks * 32 + (l >> 4) * 8 + j;
      w[j] = f2bf(Mm[k * 64 + col]);
    }
    uint4 pk;
    pk.x = (unsigned)w[0] | ((unsigned)w[1] << 16);
    pk.y = (unsigned)w[2] | ((unsigned)w[3] << 16);
    pk.z = (unsigned)w[4] | ((unsigned)w[5] << 16);
    pk.w = (unsigned)w[6] | ((unsigned)w[7] << 16);
    Bfrag[e] = pk;
  }
}

// ---------------------------------------------------------------------------
// Main R20 = R17 (best, 73.5us) + NONTEMPORAL coalesced stores.
// Mechanism: x (128MB) + out (128MB) exactly saturate the 256MB L3, so
// out-writes evict half of x each replay (FETCH 66MB). nt stores skip L3
// allocation -> x fully L3-resident -> FETCH drops, HBM carries only the
// write stream. R4's nt failure was scattered 32B dword stores (RMW); here
// each store group covers contiguous 1KB runs, so no partial-sector hazard.
// Everything else byte-identical to R17: single 16-deep DMA burst per wave
// (one vmcnt(0)/wave), M-fragments in block LDS (8KB), split-bf16 X,
// swapped-operand MFMA, in-lane RoPE via angle recurrence, swizzled
// in-place obuf transpose -> 4x contiguous 1KB dwordx4 (nt) stores.
// ---------------------------------------------------------------------------
__global__ __launch_bounds__(256)
void rotary_main(const float* __restrict__ x,
                 const uint4* __restrict__ Bfrag,
                 const float2* __restrict__ csT,
                 float* __restrict__ out) {
  __shared__ float sstage[4][4096];             // 64KB: 4 waves x 16KB group
  __shared__ uint4 sB[8 * 64];                  // 8KB M-fragments (block)
  const int tid  = threadIdx.x;
  const int lane = tid & 63;
  const int wid  = tid >> 6;
  const int g    = blockIdx.x * 4 + wid;        // group id 0..8191

  const int lr = lane & 15;                     // out row-in-tile / X row
  const int lk = lane >> 4;                     // k-block / out col-block

  // ---- prologue: Bfrag -> LDS + cs/sin bases; barrier drains ALL vmcnt ----
  #pragma unroll
  for (int i = 0; i < 2; ++i) {
    const int chunk = wid * 2 + i;              // 8 chunks over 4 waves
    __builtin_amdgcn_global_load_lds(
        (gu32*)(const void*)(Bfrag + chunk * 64 + lane),
        (lu32*)(void*)(sB + chunk * 64), 16, 0, 0);
  }
  const int s0 = (g * 4) & (S_LEN - 1);
  float4 cs[4], rt[4];
  #pragma unroll
  for (int nt = 0; nt < 4; ++nt) {
    cs[nt] = *(const float4*)(csT + s0 * 32 + nt * 8 + lk * 2);
    rt[nt] = *(const float4*)(csT + 32 + nt * 8 + lk * 2);     // s=1 row
  }
  __syncthreads();                              // vmcnt FIFO now empty

  const float* xg = x + (size_t)g * 4096;
  float* og = out + (size_t)g * 4096;
  float* buf = &sstage[wid][0];

  // stage the whole 16KB group: 16 x (64 lanes x 16B), source pre-swizzled
  // (granule ^= row&7) so per-lane row reads are bank-balanced (m173).
  #pragma unroll
  for (int q = 0; q < 16; ++q) {
    const int row = q * 4 + lk;
    const int gs  = lr ^ (row & 7);
    __builtin_amdgcn_global_load_lds(
        (gu32*)(const void*)(xg + (size_t)row * 64 + gs * 4),
        (lu32*)(void*)(buf + q * 256), 16, 0, 0);
  }
  __builtin_amdgcn_sched_barrier(0);
  asm volatile("s_waitcnt vmcnt(0)" ::: "memory");   // the ONE global wait
  __builtin_amdgcn_sched_barrier(0);

  const short8x* sBf = (const short8x*)sB;
  const int key  = lr & 7;                      // staging read swizzle
  const int okey = key << 2;                    // obuf write swizzle

  #pragma unroll
  for (int t = 0; t < 4; ++t) {
    float* qbuf = buf + t * 1024;               // this tile's quarter

    // consume: 4 bank-balanced ds_read_b128 per lane (local row = lr)
    const float* bb = qbuf + lr * 64;
    floatx4 x0 = *(const floatx4*)(bb + (((lk * 2 + 0)    ) ^ key) * 4);
    floatx4 x1 = *(const floatx4*)(bb + (((lk * 2 + 1)    ) ^ key) * 4);
    floatx4 x2 = *(const floatx4*)(bb + (((lk * 2 + 0) + 8) ^ key) * 4);
    floatx4 x3 = *(const floatx4*)(bb + (((lk * 2 + 1) + 8) ^ key) * 4);

    // convert to hi/lo bf16 (trunc hi, RNE lo)
    short8x Xh0, Xl0, Xh1, Xl1;
    #pragma unroll
    for (int i = 0; i < 8; ++i) {
      float v0 = (i < 4) ? x0[i] : x1[i - 4];
      float v1 = (i < 4) ? x2[i] : x3[i - 4];
      unsigned u0 = __builtin_bit_cast(unsigned, v0);
      unsigned u1 = __builtin_bit_cast(unsigned, v1);
      unsigned short h0 = (unsigned short)(u0 >> 16);
      unsigned short h1 = (unsigned short)(u1 >> 16);
      Xh0[i] = (short)h0; Xl0[i] = (short)f2bf(v0 - bf2f(h0));
      Xh1[i] = (short)h1; Xl1[i] = (short)f2bf(v1 - bf2f(h1));
    }

    // MFMA + in-lane RoPE; obuf = this quarter, reused in place
    #pragma unroll
    for (int nt = 0; nt < 4; ++nt) {
      short8x bh0 = sBf[(nt * 2 + 0) * 64 + lane];   // M, ks0
      short8x bh1 = sBf[(nt * 2 + 1) * 64 + lane];   // M, ks1

      floatx4 acc0 = {0.f, 0.f, 0.f, 0.f};
      floatx4 acc1 = {0.f, 0.f, 0.f, 0.f};
      acc0 = __builtin_amdgcn_mfma_f32_16x16x32_bf16(bh0, Xh0, acc0, 0, 0, 0);
      acc1 = __builtin_amdgcn_mfma_f32_16x16x32_bf16(bh1, Xh1, acc1, 0, 0, 0);
      acc0 = __builtin_amdgcn_mfma_f32_16x16x32_bf16(bh0, Xl0, acc0, 0, 0, 0);
      acc1 = __builtin_amdgcn_mfma_f32_16x16x32_bf16(bh1, Xl1, acc1, 0, 0, 0);

      // lane holds y[row=lr][cols nt*16+lk*4 .. +3] = 2 RoPE pairs in-lane
      const float a0  = acc0[0] + acc1[0];
      const float b0v = acc0[1] + acc1[1];
      const float a1  = acc0[2] + acc1[2];
      const float b1v = acc0[3] + acc1[3];
      float2 ev, od;
      ev.x = fmaf(a0, cs[nt].x, -(b0v * cs[nt].y));  // out[D]    = x1*c - x2*s
      ev.y = fmaf(a1, cs[nt].z, -(b1v * cs[nt].w));
      od.x = fmaf(a0, cs[nt].y,   b0v * cs[nt].x);   // out[32+D] = x1*s + x2*c
      od.y = fmaf(a1, cs[nt].w,   b1v * cs[nt].z);
      float* ow = qbuf + lr * 64;
      *(float2*)(ow + ((     nt * 8 + lk * 2) ^ okey)) = ev;
      *(float2*)(ow + ((32 + nt * 8 + lk * 2) ^ okey)) = od;
    }

    // advance cos/sin to next s (angle addition; 3 steps max)
    if (t < 3) {
      #pragma unroll
      for (int nt = 0; nt < 4; ++nt) {
        float c0 = cs[nt].x, s0v = cs[nt].y, c1 = cs[nt].z, s1v = cs[nt].w;
        cs[nt].x = fmaf(c0, rt[nt].x, -(s0v * rt[nt].y));
        cs[nt].y = fmaf(c0, rt[nt].y,   s0v * rt[nt].x);
        cs[nt].z = fmaf(c1, rt[nt].z, -(s1v * rt[nt].w));
        cs[nt].w = fmaf(c1, rt[nt].w,   s1v * rt[nt].z);
      }
    }

    // drain obuf writes, read back swizzled, store 4x contiguous 1KB runs
    // with NONTEMPORAL hint (skip L3 allocation; keep x resident).
    asm volatile("s_waitcnt lgkmcnt(0)" ::: "memory");
    __builtin_amdgcn_sched_barrier(0);
    #pragma unroll
    for (int q = 0; q < 4; ++q) {
      const int row = q * 4 + lk;               // local row in tile
      floatx4 vr = *(const floatx4*)(qbuf + row * 64 +
                                     ((lr * 4) ^ ((row & 7) << 2)));
      __builtin_nontemporal_store(vr,
          (floatx4*)(og + (size_t)(t * 16 + row) * 64 + lr * 4));
    }
  }
}

extern "C" void kernel_launch(void* const* d_in, const int* in_sizes, int n_in,
                              void* d_out, int out_size, void* d_ws, size_t ws_size,
                              hipStream_t stream) {
  const float* x           = (const float*)d_in[0];
  const float* thetas      = (const float*)d_in[1];
  const float* theta_scale = (const float*)d_in[2];
  const float* r_matrix    = (const float*)d_in[3];
  const float* inv_freq    = (const float*)d_in[4];
  const int*   r_pairs     = (const int*)d_in[5];

  uint4*  Bfrag = (uint4*)d_ws;                 // 8*64*16B = 8KB
  float2* csT   = (float2*)((char*)d_ws + 16384);  // 4096*32*8B = 1MB
  float*  outp  = (float*)d_out;

  setup_kernel<<<513, 256, 0, stream>>>(thetas, theta_scale, r_matrix, r_pairs,
                                        inv_freq, Bfrag, csT);
  rotary_main<<<NGRP / 4, 256, 0, stream>>>(x, Bfrag, csT, outp);
}

// Round 21
// 70.105 us; speedup vs baseline: 2.4124x; 1.0165x over previous
//
#include <hip/hip_runtime.h>
#include <cstdint>
#include <cstddef>

// Problem constants (reference: B=8, S=4096, N_STATE=1024, N_HEAD=16)
#define S_LEN   4096
#define NROT    32
#define NGRP    8192    // groups of 64 rows (64x64 fp32 tile each)

typedef __attribute__((ext_vector_type(8))) short  short8x;  // 8 bf16 (4 VGPR)
typedef __attribute__((ext_vector_type(4))) float  floatx4;  // 4 f32

typedef __attribute__((address_space(1))) unsigned int gu32;
typedef __attribute__((address_space(3))) unsigned int lu32;

__device__ __host__ inline unsigned short f2bf(float f) {
  union { float f; unsigned u; } c; c.f = f;
  unsigned u = c.u;
  return (unsigned short)((u + 0x7fffu + ((u >> 16) & 1u)) >> 16);
}
__device__ inline float bf2f(unsigned short h) {
  union { unsigned u; float f; } c; c.u = ((unsigned)h) << 16;
  return c.f;
}

// ---------------------------------------------------------------------------
// Setup: blocks 0..511 fill the interleaved cos/sin table (4096 x 32 float2).
// Block 512: compose M = G0..G31 * R, emit 8 RNE-bf16 M^T-fragments
// (nt x ks; x keeps its hi/lo split so the dominant precision path stays):
//   Bfrag[(nt*2+ks)*64 + lane] = 8 bf16:
//     M[k = ks*32 + (lane>>4)*8 + j][col = nt*16 + (lane&15)]
// ---------------------------------------------------------------------------
__global__ void setup_kernel(const float* __restrict__ thetas,
                             const float* __restrict__ theta_scale,
                             const float* __restrict__ r_matrix,
                             const int*   __restrict__ r_pairs,
                             const float* __restrict__ inv_freq,
                             uint4* __restrict__ Bfrag,
                             float2* __restrict__ csT) {
  if (blockIdx.x < 512) {
    int idx = blockIdx.x * 256 + threadIdx.x;   // 0..131071 = s*32 + f
    int s = idx >> 5;
    int f = idx & 31;
    float ang = (float)s * inv_freq[f];
    csT[idx] = make_float2(cosf(ang), sinf(ang));
    return;
  }
  __shared__ float C[64 * 65];
  __shared__ float Mm[64 * 64];
  int tid = threadIdx.x;
  if (tid < 64) {
    for (int c = 0; c < 64; ++c) C[tid * 65 + c] = (tid == c) ? 1.0f : 0.0f;
    float sc = theta_scale[0];
    for (int q = 0; q < NROT; ++q) {
      float th = thetas[q] * sc;
      float cs = cosf(th), sn = sinf(th);
      int i = r_pairs[2 * q], j = r_pairs[2 * q + 1];
      float xi = C[tid * 65 + i];
      float xj = C[tid * 65 + j];
      C[tid * 65 + i] =  xi * cs + xj * sn;
      C[tid * 65 + j] = -xi * sn + xj * cs;
    }
  }
  __syncthreads();
  for (int o = tid; o < 64 * 64; o += 256) {
    int t = o >> 6, c = o & 63;
    float a = 0.0f;
    for (int k = 0; k < 64; ++k) a = fmaf(C[t * 65 + k], r_matrix[k * 64 + c], a);
    Mm[o] = a;
  }
  __syncthreads();
  for (int e = tid; e < 8 * 64; e += 256) {
    int f = e >> 6, l = e & 63;
    int ks = f & 1, nt = f >> 1;
    int col = nt * 16 + (l & 15);
    unsigned short w[8];
    for (int j = 0; j < 8; ++j) {
      int k = ks * 32 + (l >> 4) * 8 + j;
      w[j] = f2bf(Mm[k * 64 + col]);
    }
    uint4 pk;
    pk.x = (unsigned)w[0] | ((unsigned)w[1] << 16);
    pk.y = (unsigned)w[2] | ((unsigned)w[3] << 16);
    pk.z = (unsigned)w[4] | ((unsigned)w[5] << 16);
    pk.w = (unsigned)w[6] | ((unsigned)w[7] << 16);
    Bfrag[e] = pk;
  }
}

// ---------------------------------------------------------------------------
// Main R21 = consolidation of the three individually-validated best pieces:
// (1) R14's 2-deep DMA pipeline with EXACT non-store-blocking waits
//     (issue order post-barrier: S0 S1 | t0: w(4) .. S2, st0 | t1: w(8) ..
//      S3, st1 | t2: w(12) .. st2 | t3: w(8) — each wait releases exactly
//      at S_t; FIFO-verified: no wait forces a younger store-ack).
// (2) 40KB LDS/block -> 4 blocks/CU (2x R20's block residency; halves
//     block-turnover prologue exposure).
// (3) R20's NONTEMPORAL coalesced stores (skip L3 allocation; keep x
//     L3-resident across replays; no RMW since each store group covers
//     contiguous 1KB runs — validated amp 1.00, -2.2us on R17).
// Body per tile (validated R8-R20): bank-balanced swizzled ds_read_b128 ->
// split-bf16 X -> swapped-operand MFMA (bf16 M, dual 2-deep chains) ->
// in-lane RoPE (angle recurrence) -> swizzled obuf transpose (reused stage
// buf) -> 4x contiguous 1KB dwordx4 nt stores. M-fragments in block LDS.
// ---------------------------------------------------------------------------
__global__ __launch_bounds__(256)
void rotary_main(const float* __restrict__ x,
                 const uint4* __restrict__ Bfrag,
                 const float2* __restrict__ csT,
                 float* __restrict__ out) {
  __shared__ float sstage[4][2][1024];          // 32KB: 4 waves x 2 bufs x 4KB
  __shared__ uint4 sB[8 * 64];                  // 8KB M-fragments (block)
  const int tid  = threadIdx.x;
  const int lane = tid & 63;
  const int wid  = tid >> 6;
  const int g    = blockIdx.x * 4 + wid;        // group id 0..8191

  const int lr = lane & 15;                     // out row-in-tile / X row
  const int lk = lane >> 4;                     // k-block / out col-block

  // ---- prologue: Bfrag -> LDS + cs/sin bases; barrier drains ALL vmcnt ----
  #pragma unroll
  for (int i = 0; i < 2; ++i) {
    const int chunk = wid * 2 + i;              // 8 chunks over 4 waves
    __builtin_amdgcn_global_load_lds(
        (gu32*)(const void*)(Bfrag + chunk * 64 + lane),
        (lu32*)(void*)(sB + chunk * 64), 16, 0, 0);
  }
  const int s0 = (g * 4) & (S_LEN - 1);
  float4 cs[4], rt[4];
  #pragma unroll
  for (int nt = 0; nt < 4; ++nt) {
    cs[nt] = *(const float4*)(csT + s0 * 32 + nt * 8 + lk * 2);
    rt[nt] = *(const float4*)(csT + 32 + nt * 8 + lk * 2);     // s=1 row
  }
  __syncthreads();                              // vmcnt FIFO now empty

  const float* xg = x + (size_t)g * 4096;
  float* og = out + (size_t)g * 4096;
  float* stg = &sstage[wid][0][0];

  // stage tile t into buffer b; source pre-swizzled (granule ^= row&7) so
  // the per-lane row reads below are bank-balanced (m173 pattern).
  #define STAGE(t, b) {                                                     \
    float* dst_ = stg + (b) * 1024;                                         \
    _Pragma("unroll")                                                       \
    for (int q_ = 0; q_ < 4; ++q_) {                                        \
      const int row_ = q_ * 4 + lk;                                         \
      const int gs_  = lr ^ (row_ & 7);                                     \
      __builtin_amdgcn_global_load_lds(                                     \
        (gu32*)(const void*)(xg + (size_t)((t) * 16 + row_) * 64 + gs_ * 4),\
        (lu32*)(void*)(dst_ + q_ * 256), 16, 0, 0);                         \
    }                                                                       \
  }

  STAGE(0, 0)
  STAGE(1, 1)
  __builtin_amdgcn_sched_barrier(0);

  const short8x* sBf = (const short8x*)sB;
  const int key  = lr & 7;                      // staging read swizzle
  const int okey = key << 2;                    // obuf write swizzle

  #pragma unroll
  for (int t = 0; t < 4; ++t) {
    // exact release points (FIFO derivation in header comment)
    if (t == 0)      { asm volatile("s_waitcnt vmcnt(4)"  ::: "memory"); }
    else if (t == 1) { asm volatile("s_waitcnt vmcnt(8)"  ::: "memory"); }
    else if (t == 2) { asm volatile("s_waitcnt vmcnt(12)" ::: "memory"); }
    else             { asm volatile("s_waitcnt vmcnt(8)"  ::: "memory"); }
    __builtin_amdgcn_sched_barrier(0);

    float* buf = stg + (t & 1) * 1024;

    // consume: 4 bank-balanced ds_read_b128 per lane (row = lr)
    const float* bb = buf + lr * 64;
    floatx4 x0 = *(const floatx4*)(bb + (((lk * 2 + 0)    ) ^ key) * 4);
    floatx4 x1 = *(const floatx4*)(bb + (((lk * 2 + 1)    ) ^ key) * 4);
    floatx4 x2 = *(const floatx4*)(bb + (((lk * 2 + 0) + 8) ^ key) * 4);
    floatx4 x3 = *(const floatx4*)(bb + (((lk * 2 + 1) + 8) ^ key) * 4);

    // convert to hi/lo bf16 (trunc hi, RNE lo)
    short8x Xh0, Xl0, Xh1, Xl1;
    #pragma unroll
    for (int i = 0; i < 8; ++i) {
      float v0 = (i < 4) ? x0[i] : x1[i - 4];
      float v1 = (i < 4) ? x2[i] : x3[i - 4];
      unsigned u0 = __builtin_bit_cast(unsigned, v0);
      unsigned u1 = __builtin_bit_cast(unsigned, v1);
      unsigned short h0 = (unsigned short)(u0 >> 16);
      unsigned short h1 = (unsigned short)(u1 >> 16);
      Xh0[i] = (short)h0; Xl0[i] = (short)f2bf(v0 - bf2f(h0));
      Xh1[i] = (short)h1; Xl1[i] = (short)f2bf(v1 - bf2f(h1));
    }

    // MFMA + in-lane RoPE; obuf = the staging buffer just consumed
    #pragma unroll
    for (int nt = 0; nt < 4; ++nt) {
      short8x bh0 = sBf[(nt * 2 + 0) * 64 + lane];   // M, ks0
      short8x bh1 = sBf[(nt * 2 + 1) * 64 + lane];   // M, ks1

      floatx4 acc0 = {0.f, 0.f, 0.f, 0.f};
      floatx4 acc1 = {0.f, 0.f, 0.f, 0.f};
      acc0 = __builtin_amdgcn_mfma_f32_16x16x32_bf16(bh0, Xh0, acc0, 0, 0, 0);
      acc1 = __builtin_amdgcn_mfma_f32_16x16x32_bf16(bh1, Xh1, acc1, 0, 0, 0);
      acc0 = __builtin_amdgcn_mfma_f32_16x16x32_bf16(bh0, Xl0, acc0, 0, 0, 0);
      acc1 = __builtin_amdgcn_mfma_f32_16x16x32_bf16(bh1, Xl1, acc1, 0, 0, 0);

      // lane holds y[row=lr][cols nt*16+lk*4 .. +3] = 2 RoPE pairs in-lane
      const float a0  = acc0[0] + acc1[0];
      const float b0v = acc0[1] + acc1[1];
      const float a1  = acc0[2] + acc1[2];
      const float b1v = acc0[3] + acc1[3];
      float2 ev, od;
      ev.x = fmaf(a0, cs[nt].x, -(b0v * cs[nt].y));  // out[D]    = x1*c - x2*s
      ev.y = fmaf(a1, cs[nt].z, -(b1v * cs[nt].w));
      od.x = fmaf(a0, cs[nt].y,   b0v * cs[nt].x);   // out[32+D] = x1*s + x2*c
      od.y = fmaf(a1, cs[nt].w,   b1v * cs[nt].z);
      float* ow = buf + lr * 64;
      *(float2*)(ow + ((     nt * 8 + lk * 2) ^ okey)) = ev;
      *(float2*)(ow + ((32 + nt * 8 + lk * 2) ^ okey)) = od;
    }

    // advance cos/sin to next s (angle addition; 3 steps max)
    if (t < 3) {
      #pragma unroll
      for (int nt = 0; nt < 4; ++nt) {
        float c0 = cs[nt].x, s0v = cs[nt].y, c1 = cs[nt].z, s1v = cs[nt].w;
        cs[nt].x = fmaf(c0, rt[nt].x, -(s0v * rt[nt].y));
        cs[nt].y = fmaf(c0, rt[nt].y,   s0v * rt[nt].x);
        cs[nt].z = fmaf(c1, rt[nt].z, -(s1v * rt[nt].w));
        cs[nt].w = fmaf(c1, rt[nt].w,   s1v * rt[nt].z);
      }
    }

    // drain obuf writes, read back swizzled into regs, drain reads,
    // THEN issue next stage (into this now-free buffer), THEN nt stores.
    asm volatile("s_waitcnt lgkmcnt(0)" ::: "memory");
    __builtin_amdgcn_sched_barrier(0);
    floatx4 vr[4];
    #pragma unroll
    for (int q = 0; q < 4; ++q) {
      const int row = q * 4 + lk;
      vr[q] = *(const floatx4*)(buf + row * 64 + ((lr * 4) ^ ((row & 7) << 2)));
    }
    asm volatile("s_waitcnt lgkmcnt(0)" ::: "memory");
    __builtin_amdgcn_sched_barrier(0);
    if (t < 2) STAGE(t + 2, t & 1)
    __builtin_amdgcn_sched_barrier(0);
    #pragma unroll
    for (int q = 0; q < 4; ++q) {
      const int row = q * 4 + lk;
      __builtin_nontemporal_store(vr[q],
          (floatx4*)(og + (size_t)(t * 16 + row) * 64 + lr * 4));
    }
  }
  #undef STAGE
}

extern "C" void kernel_launch(void* const* d_in, const int* in_sizes, int n_in,
                              void* d_out, int out_size, void* d_ws, size_t ws_size,
                              hipStream_t stream) {
  const float* x           = (const float*)d_in[0];
  const float* thetas      = (const float*)d_in[1];
  const float* theta_scale = (const float*)d_in[2];
  const float* r_matrix    = (const float*)d_in[3];
  const float* inv_freq    = (const float*)d_in[4];
  const int*   r_pairs     = (const int*)d_in[5];

  uint4*  Bfrag = (uint4*)d_ws;                 // 8*64*16B = 8KB
  float2* csT   = (float2*)((char*)d_ws + 16384);  // 4096*32*8B = 1MB
  float*  outp  = (float*)d_out;

  setup_kernel<<<513, 256, 0, stream>>>(thetas, theta_scale, r_matrix, r_pairs,
                                        inv_freq, Bfrag, csT);
  rotary_main<<<NGRP / 4, 256, 0, stream>>>(x, Bfrag, csT, outp);
}